// Round 1
// baseline (256.711 us; speedup 1.0000x reference)
//
#include <hip/hip_runtime.h>
#include <hip/hip_bf16.h>

#define BATCH 4096
#define DIM   2048
#define INV_T 2.0f   // 1 / TEMPERATURE, TEMPERATURE = 0.5

#define BM 128
#define BN 128
#define BK 32

typedef __bf16 bf16x8 __attribute__((ext_vector_type(8)));
typedef float  floatx4 __attribute__((ext_vector_type(4)));

static __device__ __forceinline__ unsigned short f2bf(float f) {
  unsigned int u = __float_as_uint(f);
  u += 0x7fffu + ((u >> 16) & 1u);   // round-to-nearest-even
  return (unsigned short)(u >> 16);
}
static __device__ __forceinline__ float bf2f(unsigned int h) {
  return __uint_as_float(h << 16);
}

static __device__ __forceinline__ void gld_lds16(const void* g, void* l) {
  __builtin_amdgcn_global_load_lds(
      (const __attribute__((address_space(1))) void*)g,
      (__attribute__((address_space(3))) void*)l, 16, 0, 0);
}

// ---------------------------------------------------------------------------
// Kernel 1: per-row log-softmax prep.
//   rows [0, B)    -> Li  (bf16 log_softmax(c_i) row)
//   rows [B, 2B)   -> Qb  (bf16 softmax(c_j) row) + hneg fp32 + rowsum=0
// ---------------------------------------------------------------------------
__global__ __launch_bounds__(256) void prep_kernel(
    const float* __restrict__ ci, const float* __restrict__ cj,
    unsigned short* __restrict__ Li, unsigned short* __restrict__ Qb,
    float* __restrict__ hneg, float* __restrict__ rowsum,
    float* __restrict__ out)
{
  const int tid = threadIdx.x;
  const int row = blockIdx.x;
  const bool isj = row >= BATCH;
  const int r = isj ? row - BATCH : row;
  const float* __restrict__ src = (isj ? cj : ci) + (size_t)r * DIM;

  // 8 elements per thread: [tid*4, tid*4+4) and [1024 + tid*4, ...)
  float4 va = ((const float4*)src)[tid];
  float4 vb = ((const float4*)src)[tid + 256];
  float v[8] = {va.x, va.y, va.z, va.w, vb.x, vb.y, vb.z, vb.w};

  __shared__ float red[4];

  // block max
  float m = v[0];
  #pragma unroll
  for (int i = 1; i < 8; ++i) m = fmaxf(m, v[i]);
  #pragma unroll
  for (int off = 32; off >= 1; off >>= 1) m = fmaxf(m, __shfl_xor(m, off));
  if ((tid & 63) == 0) red[tid >> 6] = m;
  __syncthreads();
  m = fmaxf(fmaxf(red[0], red[1]), fmaxf(red[2], red[3]));
  __syncthreads();

  // block sum of exp(v - m)
  float s = 0.f;
  #pragma unroll
  for (int i = 0; i < 8; ++i) s += __expf(v[i] - m);
  #pragma unroll
  for (int off = 32; off >= 1; off >>= 1) s += __shfl_xor(s, off);
  if ((tid & 63) == 0) red[tid >> 6] = s;
  __syncthreads();
  s = red[0] + red[1] + red[2] + red[3];
  const float ls = m + __logf(s);          // logsumexp of row

  unsigned short w[8];
  float h = 0.f;
  #pragma unroll
  for (int i = 0; i < 8; ++i) {
    const float li = v[i] - ls;            // log_softmax element
    if (isj) {
      const float q = __expf(li);          // softmax element
      h += q * li;                         // negative entropy accum
      w[i] = f2bf(q);
    } else {
      w[i] = f2bf(li);
    }
  }
  unsigned short* dst = (isj ? Qb : Li) + (size_t)r * DIM;
  ((ushort4*)dst)[tid]       = make_ushort4(w[0], w[1], w[2], w[3]);
  ((ushort4*)dst)[tid + 256] = make_ushort4(w[4], w[5], w[6], w[7]);

  if (isj) {
    __syncthreads();
    #pragma unroll
    for (int off = 32; off >= 1; off >>= 1) h += __shfl_xor(h, off);
    if ((tid & 63) == 0) red[tid >> 6] = h;
    __syncthreads();
    if (tid == 0) {
      hneg[r] = red[0] + red[1] + red[2] + red[3];
      rowsum[r] = 0.f;
    }
  }
  if (row == 0 && tid == 0) out[0] = 0.f;
}

// ---------------------------------------------------------------------------
// Kernel 2: cross = Li @ Qb^T (bf16 MFMA, 128x128 tile) with fused
// epilogue: rowsum[i] += sum_j exp(INV_T * (cross[i,j] - hneg[j])).
// Safe without max-subtraction: KL >= 0 => logits <= ~0, exp <= ~1.
// m97 structure: global_load_lds width-16 staging, 2-barrier K-loop.
// ---------------------------------------------------------------------------
__global__ __launch_bounds__(256) void gemm_lse_kernel(
    const unsigned short* __restrict__ Li, const unsigned short* __restrict__ Qb,
    const float* __restrict__ hneg, float* __restrict__ rowsum)
{
  __shared__ unsigned short As[BM * BK];   // 8 KB
  __shared__ unsigned short Bs[BN * BK];   // 8 KB

  const int tid  = threadIdx.x;
  const int bx   = blockIdx.x;             // N tile index
  const int by   = blockIdx.y;             // M tile index
  const int lane = tid & 63;
  const int wave = tid >> 6;
  const int wm   = (wave >> 1) * 64;       // wave row offset within tile
  const int wn   = (wave & 1) * 64;        // wave col offset within tile

  // staging: 512 chunks of 16B per operand; thread t handles chunks t, t+256
  const int srow = tid >> 2;               // 0..63  (chunk row; 4 chunks/row)
  const int scol = (tid & 3) << 3;         // bf16 column within row
  const unsigned short* gA = Li + (size_t)(by * BM + srow) * DIM + scol;
  const unsigned short* gB = Qb + (size_t)(bx * BN + srow) * DIM + scol;
  const size_t rstep = (size_t)64 * DIM;   // +64 rows for second chunk
  unsigned short* lA = &As[tid * 8];       // = uniform + lane*16B within wave
  unsigned short* lB = &Bs[tid * 8];

  const int rl = lane & 15;                // MFMA row-in-frag / col-in-CD
  const int kq = (lane >> 4) << 3;         // k base for this lane's quad

  floatx4 acc[4][4];
  const floatx4 z = {0.f, 0.f, 0.f, 0.f};
  #pragma unroll
  for (int mt = 0; mt < 4; ++mt)
    #pragma unroll
    for (int nt = 0; nt < 4; ++nt) acc[mt][nt] = z;

  for (int k = 0; k < DIM; k += BK) {
    gld_lds16(gA + k,         lA);
    gld_lds16(gA + k + rstep, lA + 2048);
    gld_lds16(gB + k,         lB);
    gld_lds16(gB + k + rstep, lB + 2048);
    __syncthreads();   // drains vmcnt before barrier

    bf16x8 af[4], bfr[4];
    #pragma unroll
    for (int t = 0; t < 4; ++t) {
      af[t]  = *(const bf16x8*)&As[(wm + t * 16 + rl) * BK + kq];
      bfr[t] = *(const bf16x8*)&Bs[(wn + t * 16 + rl) * BK + kq];
    }
    #pragma unroll
    for (int mt = 0; mt < 4; ++mt)
      #pragma unroll
      for (int nt = 0; nt < 4; ++nt)
        acc[mt][nt] = __builtin_amdgcn_mfma_f32_16x16x32_bf16(
            af[mt], bfr[nt], acc[mt][nt], 0, 0, 0);
    __syncthreads();
  }

  // epilogue: C/D layout col = lane&15, row = (lane>>4)*4 + reg
  const int col0 = bx * BN + wn + rl;
  float hn[4];
  #pragma unroll
  for (int nt = 0; nt < 4; ++nt) hn[nt] = hneg[col0 + nt * 16];
  const int row0 = by * BM + wm + ((lane >> 4) << 2);

  #pragma unroll
  for (int mt = 0; mt < 4; ++mt) {
    #pragma unroll
    for (int rr = 0; rr < 4; ++rr) {
      float p = 0.f;
      #pragma unroll
      for (int nt = 0; nt < 4; ++nt)
        p += __expf(INV_T * (acc[mt][nt][rr] - hn[nt]));
      // reduce across 16 cols (lane&15 group)
      p += __shfl_xor(p, 1);
      p += __shfl_xor(p, 2);
      p += __shfl_xor(p, 4);
      p += __shfl_xor(p, 8);
      if (rl == 0)
        atomicAdd(&rowsum[row0 + mt * 16 + rr], p);
    }
  }
}

// ---------------------------------------------------------------------------
// Kernel 3: loss = (1/B) sum_i [ log(rowsum[i]) - INV_T*(diag_i - hneg[i]) ]
// diag_i = dot(Li[i], Qb[i]) computed in fp32 from the bf16 rows.
// One wave per row, 4 rows per block.
// ---------------------------------------------------------------------------
__global__ __launch_bounds__(256) void finalize_kernel(
    const unsigned short* __restrict__ Li, const unsigned short* __restrict__ Qb,
    const float* __restrict__ hneg, const float* __restrict__ rowsum,
    float* __restrict__ out)
{
  const int lane = threadIdx.x & 63;
  const int wave = threadIdx.x >> 6;
  const int row = blockIdx.x * 4 + wave;
  const unsigned short* a = Li + (size_t)row * DIM;
  const unsigned short* b = Qb + (size_t)row * DIM;

  float dot = 0.f;
  #pragma unroll
  for (int i = 0; i < 4; ++i) {
    const uint4 ua = *(const uint4*)(a + (i * 64 + lane) * 8);
    const uint4 ub = *(const uint4*)(b + (i * 64 + lane) * 8);
    const unsigned int pa[4] = {ua.x, ua.y, ua.z, ua.w};
    const unsigned int pb[4] = {ub.x, ub.y, ub.z, ub.w};
    #pragma unroll
    for (int j = 0; j < 4; ++j) {
      dot += bf2f(pa[j] & 0xffffu) * bf2f(pb[j] & 0xffffu);
      dot += bf2f(pa[j] >> 16)     * bf2f(pb[j] >> 16);
    }
  }
  #pragma unroll
  for (int off = 32; off >= 1; off >>= 1) dot += __shfl_xor(dot, off);

  if (lane == 0) {
    const float contrib = __logf(rowsum[row]) - INV_T * (dot - hneg[row]);
    atomicAdd(out, contrib * (1.0f / BATCH));
  }
}

// ---------------------------------------------------------------------------
extern "C" void kernel_launch(void* const* d_in, const int* in_sizes, int n_in,
                              void* d_out, int out_size, void* d_ws, size_t ws_size,
                              hipStream_t stream) {
  const float* ci = (const float*)d_in[0];
  const float* cj = (const float*)d_in[1];
  float* out = (float*)d_out;

  // workspace layout: Li bf16 [B*D] | Qb bf16 [B*D] | hneg f32 [B] | rowsum f32 [B]
  unsigned short* Li = (unsigned short*)d_ws;
  unsigned short* Qb = Li + (size_t)BATCH * DIM;
  float* hneg   = (float*)(Qb + (size_t)BATCH * DIM);
  float* rowsum = hneg + BATCH;

  prep_kernel<<<2 * BATCH, 256, 0, stream>>>(ci, cj, Li, Qb, hneg, rowsum, out);
  dim3 grid(BATCH / BN, BATCH / BM);
  gemm_lse_kernel<<<grid, 256, 0, stream>>>(Li, Qb, hneg, rowsum);
  finalize_kernel<<<BATCH / 4, 256, 0, stream>>>(Li, Qb, hneg, rowsum, out);
}

// Round 2
// 183.907 us; speedup vs baseline: 1.3959x; 1.3959x over previous
//
#include <hip/hip_runtime.h>
#include <hip/hip_bf16.h>

#define BATCH 4096
#define DIM   2048
#define INV_T 2.0f   // 1 / TEMPERATURE, TEMPERATURE = 0.5

#define BM 128
#define BN 128

typedef __bf16 bf16x8 __attribute__((ext_vector_type(8)));
typedef float  floatx4 __attribute__((ext_vector_type(4)));

static __device__ __forceinline__ unsigned short f2bf(float f) {
  unsigned int u = __float_as_uint(f);
  u += 0x7fffu + ((u >> 16) & 1u);   // round-to-nearest-even
  return (unsigned short)(u >> 16);
}

static __device__ __forceinline__ void gld_lds16(const void* g, void* l) {
  __builtin_amdgcn_global_load_lds(
      (const __attribute__((address_space(1))) void*)g,
      (__attribute__((address_space(3))) void*)l, 16, 0, 0);
}

// ---------------------------------------------------------------------------
// Kernel 1: per-row log-softmax prep. Wave-per-row, NO barriers.
//   rows [0, B)    -> Li  (bf16 log_softmax(c_i) row)
//   rows [B, 2B)   -> Qb  (bf16 softmax(c_j) row) + hneg fp32 + rowsum=0
// ---------------------------------------------------------------------------
__global__ __launch_bounds__(256) void prep_kernel(
    const float* __restrict__ ci, const float* __restrict__ cj,
    unsigned short* __restrict__ Li, unsigned short* __restrict__ Qb,
    float* __restrict__ hneg, float* __restrict__ rowsum,
    float* __restrict__ out)
{
  const int lane = threadIdx.x & 63;
  const int wave = threadIdx.x >> 6;
  const int row = blockIdx.x * 4 + wave;
  const bool isj = row >= BATCH;
  const int r = isj ? row - BATCH : row;
  const float* __restrict__ src = (isj ? cj : ci) + (size_t)r * DIM;

  // 32 elements per lane: float4 chunks at [i*64 + lane], i = 0..7
  float v[32];
  #pragma unroll
  for (int i = 0; i < 8; ++i) {
    float4 t = ((const float4*)src)[i * 64 + lane];
    v[i * 4 + 0] = t.x; v[i * 4 + 1] = t.y;
    v[i * 4 + 2] = t.z; v[i * 4 + 3] = t.w;
  }

  // wave max
  float m = v[0];
  #pragma unroll
  for (int i = 1; i < 32; ++i) m = fmaxf(m, v[i]);
  #pragma unroll
  for (int off = 32; off >= 1; off >>= 1) m = fmaxf(m, __shfl_xor(m, off));

  // wave sum of exp(v - m)
  float s = 0.f;
  #pragma unroll
  for (int i = 0; i < 32; ++i) s += __expf(v[i] - m);
  #pragma unroll
  for (int off = 32; off >= 1; off >>= 1) s += __shfl_xor(s, off);
  const float ls = m + __logf(s);          // logsumexp of row

  unsigned short* dst = (isj ? Qb : Li) + (size_t)r * DIM;
  float h = 0.f;
  #pragma unroll
  for (int i = 0; i < 8; ++i) {
    unsigned short w[4];
    #pragma unroll
    for (int j = 0; j < 4; ++j) {
      const float li = v[i * 4 + j] - ls;  // log_softmax element
      if (isj) {
        const float q = __expf(li);        // softmax element
        h += q * li;                       // negative entropy accum
        w[j] = f2bf(q);
      } else {
        w[j] = f2bf(li);
      }
    }
    ((ushort4*)dst)[i * 64 + lane] = make_ushort4(w[0], w[1], w[2], w[3]);
  }

  if (isj) {
    #pragma unroll
    for (int off = 32; off >= 1; off >>= 1) h += __shfl_xor(h, off);
    if (lane == 0) { hneg[r] = h; rowsum[r] = 0.f; }
  }
  if (row == 0 && lane == 0) out[0] = 0.f;
}

// ---------------------------------------------------------------------------
// Kernel 2: cross = Li @ Qb^T (bf16 MFMA, 128x128 tile, BK=64 via two
// k-panels of the BK=32 layout) with fused epilogue:
//   rowsum[i] += sum_j exp(INV_T * (cross[i,j] - hneg[j]))   (atomics)
//   diag[i]    = cross[i,i]                                  (bx==by blocks)
// Safe without max-subtraction: KL >= 0 => logits <= ~0, exp <= ~1.
// ---------------------------------------------------------------------------
__global__ __launch_bounds__(256) void gemm_lse_kernel(
    const unsigned short* __restrict__ Li, const unsigned short* __restrict__ Qb,
    const float* __restrict__ hneg, float* __restrict__ rowsum,
    float* __restrict__ diag)
{
  // two 8KB panels per operand: panel p holds cols [p*32, p*32+32)
  __shared__ unsigned short As[2 * BM * 32];   // 16 KB
  __shared__ unsigned short Bs[2 * BN * 32];   // 16 KB

  const int tid  = threadIdx.x;
  const int bx   = blockIdx.x;             // N tile index
  const int by   = blockIdx.y;             // M tile index
  const int lane = tid & 63;
  const int wave = tid >> 6;
  const int wm   = (wave >> 1) * 64;       // wave row offset within tile
  const int wn   = (wave & 1) * 64;        // wave col offset within tile

  // staging: per panel, 512 chunks of 16B per operand; thread t: chunks t, t+256
  const int srow = tid >> 2;               // 0..63
  const int scol = (tid & 3) << 3;         // bf16 column within panel
  const unsigned short* gA = Li + (size_t)(by * BM + srow) * DIM + scol;
  const unsigned short* gB = Qb + (size_t)(bx * BN + srow) * DIM + scol;
  const size_t rstep = (size_t)64 * DIM;   // +64 rows for second chunk
  unsigned short* lA = &As[tid * 8];       // uniform + lane*16B within wave
  unsigned short* lB = &Bs[tid * 8];

  const int rl = lane & 15;                // MFMA row-in-frag / col-in-CD
  const int kq = (lane >> 4) << 3;         // k base for this lane's quad

  floatx4 acc[4][4];
  const floatx4 z = {0.f, 0.f, 0.f, 0.f};
  #pragma unroll
  for (int mt = 0; mt < 4; ++mt)
    #pragma unroll
    for (int nt = 0; nt < 4; ++nt) acc[mt][nt] = z;

  for (int k = 0; k < DIM; k += 64) {
    #pragma unroll
    for (int p = 0; p < 2; ++p) {
      gld_lds16(gA + k + p * 32,         lA + p * 4096);
      gld_lds16(gA + k + p * 32 + rstep, lA + p * 4096 + 2048);
      gld_lds16(gB + k + p * 32,         lB + p * 4096);
      gld_lds16(gB + k + p * 32 + rstep, lB + p * 4096 + 2048);
    }
    __syncthreads();   // drains vmcnt before barrier

    #pragma unroll
    for (int s2 = 0; s2 < 2; ++s2) {
      bf16x8 af[4], bfr[4];
      #pragma unroll
      for (int t = 0; t < 4; ++t) {
        af[t]  = *(const bf16x8*)&As[s2 * 4096 + (wm + t * 16 + rl) * 32 + kq];
        bfr[t] = *(const bf16x8*)&Bs[s2 * 4096 + (wn + t * 16 + rl) * 32 + kq];
      }
      #pragma unroll
      for (int mt = 0; mt < 4; ++mt)
        #pragma unroll
        for (int nt = 0; nt < 4; ++nt)
          acc[mt][nt] = __builtin_amdgcn_mfma_f32_16x16x32_bf16(
              af[mt], bfr[nt], acc[mt][nt], 0, 0, 0);
    }
    __syncthreads();
  }

  // ---- diag extraction: C/D layout col = lane&15, row = quad*4 + reg ----
  // diag element lives in frag (mt, mt) at reg rr = rl - 4*quad, lanes with
  // quad == rl>>2, in waves with wm == wn, blocks with bx == by.
  if (bx == by && wm == wn && (lane >> 4) == (rl >> 2)) {
    #pragma unroll
    for (int mt = 0; mt < 4; ++mt)
      diag[by * BM + wm + mt * 16 + rl] = acc[mt][mt][rl & 3];
  }

  // ---- rowsum epilogue ----
  const int col0 = bx * BN + wn + rl;
  float hn[4];
  #pragma unroll
  for (int nt = 0; nt < 4; ++nt) hn[nt] = hneg[col0 + nt * 16];
  const int row0 = by * BM + wm + ((lane >> 4) << 2);

  #pragma unroll
  for (int mt = 0; mt < 4; ++mt) {
    #pragma unroll
    for (int rr = 0; rr < 4; ++rr) {
      float p = 0.f;
      #pragma unroll
      for (int nt = 0; nt < 4; ++nt)
        p += __expf(INV_T * (acc[mt][nt][rr] - hn[nt]));
      // reduce across 16 cols (lane&15 group)
      p += __shfl_xor(p, 1);
      p += __shfl_xor(p, 2);
      p += __shfl_xor(p, 4);
      p += __shfl_xor(p, 8);
      if (rl == 0)
        atomicAdd(&rowsum[row0 + mt * 16 + rr], p);
    }
  }
}

// ---------------------------------------------------------------------------
// Kernel 3: loss = (1/B) sum_i [ log(rowsum[i]) - INV_T*(diag[i] - hneg[i]) ]
// Tiny: 48 KB of reads. 16 blocks x 256 threads, one row per thread.
// ---------------------------------------------------------------------------
__global__ __launch_bounds__(256) void finalize_kernel(
    const float* __restrict__ hneg, const float* __restrict__ rowsum,
    const float* __restrict__ diag, float* __restrict__ out)
{
  const int i = blockIdx.x * 256 + threadIdx.x;
  const int lane = threadIdx.x & 63;
  const int wave = threadIdx.x >> 6;

  float c = __logf(rowsum[i]) - INV_T * (diag[i] - hneg[i]);
  #pragma unroll
  for (int off = 32; off >= 1; off >>= 1) c += __shfl_xor(c, off);

  __shared__ float red[4];
  if (lane == 0) red[wave] = c;
  __syncthreads();
  if (threadIdx.x == 0)
    atomicAdd(out, (red[0] + red[1] + red[2] + red[3]) * (1.0f / BATCH));
}

// ---------------------------------------------------------------------------
extern "C" void kernel_launch(void* const* d_in, const int* in_sizes, int n_in,
                              void* d_out, int out_size, void* d_ws, size_t ws_size,
                              hipStream_t stream) {
  const float* ci = (const float*)d_in[0];
  const float* cj = (const float*)d_in[1];
  float* out = (float*)d_out;

  // ws: Li bf16 [B*D] | Qb bf16 [B*D] | hneg f32 [B] | rowsum f32 [B] | diag f32 [B]
  unsigned short* Li = (unsigned short*)d_ws;
  unsigned short* Qb = Li + (size_t)BATCH * DIM;
  float* hneg   = (float*)(Qb + (size_t)BATCH * DIM);
  float* rowsum = hneg + BATCH;
  float* diag   = rowsum + BATCH;

  prep_kernel<<<2 * BATCH / 4, 256, 0, stream>>>(ci, cj, Li, Qb, hneg, rowsum, out);
  dim3 grid(BATCH / BN, BATCH / BM);
  gemm_lse_kernel<<<grid, 256, 0, stream>>>(Li, Qb, hneg, rowsum, diag);
  finalize_kernel<<<BATCH / 256, 256, 0, stream>>>(hneg, rowsum, diag, out);
}